// Round 8
// baseline (149.888 us; speedup 1.0000x reference)
//
#include <hip/hip_runtime.h>
#include <stdint.h>
#include <math.h>

#define N_NODES 50000
#define N_EDGES 1500000
#define HDIM 128
#define TDIM 100
#define BM 64            // nodes per gemm tile
#define NTILES ((N_NODES + BM - 1) / BM)   // 782

typedef __attribute__((ext_vector_type(8))) short short8v;
typedef __attribute__((ext_vector_type(4))) float f32x4;

__device__ __forceinline__ unsigned short f2bf(float x) {
    unsigned int u = __float_as_uint(x);
    return (unsigned short)((u + 0x7fffu + ((u >> 16) & 1u)) >> 16);
}
__device__ __forceinline__ float sigmoidf_(float x) { return 1.0f / (1.0f + __expf(-x)); }
__device__ __forceinline__ float tanhf_(float x) { return 2.0f / (1.0f + __expf(-2.0f * x)) - 1.0f; }

__global__ void init_keys_kernel(unsigned long long* __restrict__ keys) {
    int i = blockIdx.x * 256 + threadIdx.x;
    if (i < N_NODES) keys[i] = 0ULL;
}

__global__ void scan_edges_kernel(const int* __restrict__ dst,
                                  const float* __restrict__ edge_ts,
                                  unsigned long long* __restrict__ keys) {
    int e = blockIdx.x * 256 + threadIdx.x;
    if (e < N_EDGES) {
        unsigned tsb = __float_as_uint(edge_ts[e]);   // ts>=0: bits order-preserving
        int d = dst[e];
        // hi-word filter: hi is monotone non-decreasing; 32b load can't tear.
        // tsb < hi => full key strictly loses => safe skip. Ties still atomic.
        unsigned cur_hi = ((const unsigned*)keys)[2 * d + 1];
        if (tsb >= cur_hi) {
            unsigned long long key =
                ((unsigned long long)tsb << 32) | (unsigned int)(e + 1);
            atomicMax(&keys[d], key);
        }
    }
}

// Frag-major W: wbF1[bIdx][kt][lane][8], bIdx=(g3*4+nq)*2+nf, kt 0..15 (W_ih, K-pad 512)
//              wbF2[bIdx][kt][lane][8], kt 0..3 (W_hh, K=128)
__global__ void convert_w_kernel(const float* __restrict__ Wih, const float* __restrict__ Whh,
                                 unsigned short* __restrict__ wbF1, unsigned short* __restrict__ wbF2) {
    int t = blockIdx.x * 256 + threadIdx.x;
    if (t < 24576) {
        int b = t >> 10, kt = (t >> 6) & 15, l = t & 63;
        int g3 = b >> 3, nq = (b >> 1) & 3, nf = b & 1;
        int srow = g3 * 128 + nq * 32 + nf * 16 + (l & 15);
        int scol = kt * 32 + (l >> 4) * 8;
        unsigned short v[8];
        #pragma unroll
        for (int j = 0; j < 8; ++j)
            v[j] = (scol + j < 484) ? f2bf(Wih[srow * 484 + scol + j]) : (unsigned short)0;
        uint4 pk;
        pk.x = (unsigned)v[0] | ((unsigned)v[1] << 16);
        pk.y = (unsigned)v[2] | ((unsigned)v[3] << 16);
        pk.z = (unsigned)v[4] | ((unsigned)v[5] << 16);
        pk.w = (unsigned)v[6] | ((unsigned)v[7] << 16);
        *(uint4*)&wbF1[(size_t)t * 8] = pk;
    } else if (t < 24576 + 6144) {
        int t2 = t - 24576;
        int b = t2 >> 8, kt = (t2 >> 6) & 3, l = t2 & 63;
        int g3 = b >> 3, nq = (b >> 1) & 3, nf = b & 1;
        int srow = g3 * 128 + nq * 32 + nf * 16 + (l & 15);
        int scol = kt * 32 + (l >> 4) * 8;
        unsigned short v[8];
        #pragma unroll
        for (int j = 0; j < 8; ++j) v[j] = f2bf(Whh[srow * 128 + scol + j]);
        uint4 pk;
        pk.x = (unsigned)v[0] | ((unsigned)v[1] << 16);
        pk.y = (unsigned)v[2] | ((unsigned)v[3] << 16);
        pk.z = (unsigned)v[4] | ((unsigned)v[5] << 16);
        pk.w = (unsigned)v[6] | ((unsigned)v[7] << 16);
        *(uint4*)&wbF2[(size_t)t2 * 8] = pk;
    }
}

// Build m_bar in MFMA-FRAGMENT-MAJOR layout:
//   Abuf[(((mtile*4 + mf)*16 + kt)*64 + lane)*8 + j]  (bf16)
// holds A[row = mtile*64 + mf*16 + (lane&15)][k = kt*32 + (lane>>4)*8 + j].
// No LDS, no barriers: pure gather -> pack -> coalesced write (64-thread
// groups write contiguous 1 KB). Rows: [mem[src] | mem[n] | ef[w] | tenc | 0pad].
__global__ __launch_bounds__(256)
void stage_kernel(const int* __restrict__ src, const float* __restrict__ edge_ts,
                  const float* __restrict__ ef, const float* __restrict__ mem,
                  const float* __restrict__ lut, const float* __restrict__ tw,
                  const float* __restrict__ tb, const unsigned long long* __restrict__ keys,
                  unsigned short* __restrict__ Abuf, float* __restrict__ out) {
    const int tid = threadIdx.x;
    const int gi = blockIdx.x * (256 / 4) + (tid >> 2);   // node slot 0..50047
    const int l4 = tid & 3;
    if (gi >= NTILES * BM) return;
    const int mtile = gi >> 6, i = gi & 63;
    const int mf = i >> 4, lr = i & 15;
    const int lane = l4 * 16 + lr;
    unsigned short* abase = Abuf + ((size_t)mtile * 4 + mf) * 16 * 64 * 8;

    if (gi >= N_NODES) {   // pad rows: zeros
        uint4 z = {0u, 0u, 0u, 0u};
        #pragma unroll
        for (int p = 0; p < 16; ++p)
            *(uint4*)&abase[((size_t)p * 64 + lane) * 8] = z;
        return;
    }

    const int n = gi;
    unsigned long long key = keys[n];
    const int has = (key != 0ULL);
    const int e = has ? (int)((unsigned)key - 1u) : 0;
    const int s = src[e];
    const float tv = edge_ts[e];
    const float d = tv - lut[s];
    if (l4 == 0) out[(size_t)N_NODES * HDIM + n] = has ? tv : lut[n];

    #pragma unroll
    for (int p = 0; p < 16; ++p) {
        const int k0 = p * 32 + l4 * 8;      // this thread's 8-elem group
        float f[8];
        if (k0 < 384) {
            const float* sp = (k0 < 128) ? mem + (size_t)s * HDIM + k0
                            : (k0 < 256) ? mem + (size_t)n * HDIM + (k0 - 128)
                                         : ef + (size_t)e * HDIM + (k0 - 256);
            float4 v0 = *(const float4*)sp;
            float4 v1 = *(const float4*)(sp + 4);
            f[0]=v0.x; f[1]=v0.y; f[2]=v0.z; f[3]=v0.w;
            f[4]=v1.x; f[5]=v1.y; f[6]=v1.z; f[7]=v1.w;
        } else {
            #pragma unroll
            for (int j2 = 0; j2 < 8; ++j2) {
                int q = k0 - 384 + j2;
                f[j2] = (q < TDIM) ? cosf(fmaf(d, tw[q], tb[q])) : 0.f;
            }
        }
        uint4 pk;
        pk.x = (unsigned)f2bf(f[0]) | ((unsigned)f2bf(f[1]) << 16);
        pk.y = (unsigned)f2bf(f[2]) | ((unsigned)f2bf(f[3]) << 16);
        pk.z = (unsigned)f2bf(f[4]) | ((unsigned)f2bf(f[5]) << 16);
        pk.w = (unsigned)f2bf(f[6]) | ((unsigned)f2bf(f[7]) << 16);
        *(uint4*)&abase[((size_t)p * 64 + lane) * 8] = pk;
    }
}

// Streaming GEMM: NO LDS, NO barriers. Both A and B fragment-major in global;
// every load is a coalesced 1 KB/wave dwordx4. 4 waves = 4 N-quarters; each
// wave computes 64 rows x 32 cols of each gate.
__global__ __launch_bounds__(256, 2)
void gemm_kernel(const unsigned short* __restrict__ Abuf,
                 const unsigned short* __restrict__ wbF1,
                 const unsigned short* __restrict__ wbF2,
                 const float* __restrict__ bih, const float* __restrict__ bhh,
                 const float* __restrict__ mem,
                 const unsigned long long* __restrict__ keys,
                 float* __restrict__ out) {
    const int tid = threadIdx.x;
    const int bid = blockIdx.x;
    const int base = bid * BM;
    const int nq = tid >> 6, l = tid & 63;
    const int lr = l & 15, lh = l >> 4;
    const unsigned short* abase = Abuf + (size_t)bid * 4 * 16 * 64 * 8;

    const f32x4 fzero = {0.f, 0.f, 0.f, 0.f};
    f32x4 acc[4][2][4];  // q=0 r(i+h), q=1 z(i+h), q=2 i_n, q=3 h_n
    #pragma unroll
    for (int q = 0; q < 4; ++q)
        #pragma unroll
        for (int nf = 0; nf < 2; ++nf)
            #pragma unroll
            for (int mf = 0; mf < 4; ++mf) acc[q][nf][mf] = fzero;

    // GEMM1: gi = A(K=512) @ W_ih^T
    #pragma unroll 4
    for (int kt = 0; kt < 16; ++kt) {
        short8v a[4];
        #pragma unroll
        for (int mf = 0; mf < 4; ++mf)
            a[mf] = *(const short8v*)&abase[(((size_t)mf * 16 + kt) * 64 + l) * 8];
        #pragma unroll
        for (int g3 = 0; g3 < 3; ++g3)
            #pragma unroll
            for (int nf = 0; nf < 2; ++nf) {
                const int bidx = (g3 * 4 + nq) * 2 + nf;
                short8v b = *(const short8v*)&wbF1[((size_t)(bidx * 16 + kt) * 64 + l) * 8];
                #pragma unroll
                for (int mf = 0; mf < 4; ++mf)
                    acc[g3][nf][mf] = __builtin_amdgcn_mfma_f32_16x16x32_bf16(
                        a[mf], b, acc[g3][nf][mf], 0, 0, 0);
            }
    }
    // GEMM2: gh = mem_s @ W_hh^T  (A k-slice 128..256 = kt 4..7)
    #pragma unroll
    for (int kt2 = 0; kt2 < 4; ++kt2) {
        short8v a[4];
        #pragma unroll
        for (int mf = 0; mf < 4; ++mf)
            a[mf] = *(const short8v*)&abase[(((size_t)mf * 16 + (4 + kt2)) * 64 + l) * 8];
        #pragma unroll
        for (int g3 = 0; g3 < 3; ++g3)
            #pragma unroll
            for (int nf = 0; nf < 2; ++nf) {
                const int bidx = (g3 * 4 + nq) * 2 + nf;
                short8v b = *(const short8v*)&wbF2[((size_t)(bidx * 4 + kt2) * 64 + l) * 8];
                const int q = (g3 < 2) ? g3 : 3;
                #pragma unroll
                for (int mf = 0; mf < 4; ++mf)
                    acc[q][nf][mf] = __builtin_amdgcn_mfma_f32_16x16x32_bf16(
                        a[mf], b, acc[q][nf][mf], 0, 0, 0);
            }
    }

    // ---- GRU epilogue ----
    float br[2], bz[2], bin[2], bhn[2];
    #pragma unroll
    for (int nf = 0; nf < 2; ++nf) {
        const int c = nq * 32 + nf * 16 + lr;
        br[nf] = bih[c] + bhh[c];
        bz[nf] = bih[HDIM + c] + bhh[HDIM + c];
        bin[nf] = bih[2 * HDIM + c];
        bhn[nf] = bhh[2 * HDIM + c];
    }
    #pragma unroll
    for (int mf = 0; mf < 4; ++mf)
        #pragma unroll
        for (int ii = 0; ii < 4; ++ii) {
            const int row = mf * 16 + lh * 4 + ii;
            const int node = base + row;
            if (node >= N_NODES) continue;
            const bool has = keys[node] != 0ULL;
            #pragma unroll
            for (int nf = 0; nf < 2; ++nf) {
                const int c = nq * 32 + nf * 16 + lr;
                const float r = sigmoidf_(acc[0][nf][mf][ii] + br[nf]);
                const float z = sigmoidf_(acc[1][nf][mf][ii] + bz[nf]);
                const float ng = tanhf_(acc[2][nf][mf][ii] + bin[nf] +
                                        r * (acc[3][nf][mf][ii] + bhn[nf]));
                const float h = mem[(size_t)node * HDIM + c];
                out[(size_t)node * HDIM + c] = has ? (1.f - z) * ng + z * h : h;
            }
        }
}

extern "C" void kernel_launch(void* const* d_in, const int* in_sizes, int n_in,
                              void* d_out, int out_size, void* d_ws, size_t ws_size,
                              hipStream_t stream) {
    const int* src       = (const int*)d_in[0];
    const int* dst       = (const int*)d_in[1];
    const float* edge_ts = (const float*)d_in[2];
    const float* ef      = (const float*)d_in[3];
    const float* mem     = (const float*)d_in[4];
    const float* lut     = (const float*)d_in[5];
    const float* tw      = (const float*)d_in[6];
    const float* tb      = (const float*)d_in[7];
    const float* Wih     = (const float*)d_in[8];
    const float* Whh     = (const float*)d_in[9];
    const float* bih     = (const float*)d_in[10];
    const float* bhh     = (const float*)d_in[11];
    float* out = (float*)d_out;

    char* ws = (char*)d_ws;
    unsigned long long* keys = (unsigned long long*)ws;        // 400000 B (region 512K)
    unsigned short* wbF1 = (unsigned short*)(ws + 524288);     // 393216 B
    unsigned short* wbF2 = (unsigned short*)(ws + 917504);     //  98304 B
    unsigned short* Abuf = (unsigned short*)(ws + 2097152);    // 782*64KB = 51.2 MB

    init_keys_kernel<<<(N_NODES + 255) / 256, 256, 0, stream>>>(keys);
    scan_edges_kernel<<<(N_EDGES + 255) / 256, 256, 0, stream>>>(dst, edge_ts, keys);
    convert_w_kernel<<<(24576 + 6144 + 255) / 256, 256, 0, stream>>>(Wih, Whh, wbF1, wbF2);
    stage_kernel<<<(NTILES * BM * 4 + 255) / 256, 256, 0, stream>>>(
        src, edge_ts, ef, mem, lut, tw, tb, keys, Abuf, out);
    gemm_kernel<<<NTILES, 256, 0, stream>>>(
        Abuf, wbF1, wbF2, bih, bhh, mem, keys, out);
}

// Round 9
// 143.967 us; speedup vs baseline: 1.0411x; 1.0411x over previous
//
#include <hip/hip_runtime.h>
#include <stdint.h>
#include <math.h>

#define N_NODES 50000
#define N_EDGES 1500000
#define HDIM 128
#define TDIM 100
#define KPAD 512         // 484 padded to multiple of 32
#define BM 128           // nodes per gru block
#define NT 512           // 8 waves = 2 mh x 4 nq
#define NBLOCKS ((N_NODES + BM - 1) / BM)   // 391

typedef __attribute__((ext_vector_type(8))) short short8v;
typedef __attribute__((ext_vector_type(4))) float f32x4;

__device__ __forceinline__ unsigned short f2bf(float x) {
    unsigned int u = __float_as_uint(x);
    return (unsigned short)((u + 0x7fffu + ((u >> 16) & 1u)) >> 16);
}
__device__ __forceinline__ float sigmoidf_(float x) { return 1.0f / (1.0f + __expf(-x)); }
__device__ __forceinline__ float tanhf_(float x) { return 2.0f / (1.0f + __expf(-2.0f * x)) - 1.0f; }

__global__ void scan_edges_kernel(const int* __restrict__ dst,
                                  const float* __restrict__ edge_ts,
                                  unsigned long long* __restrict__ keys) {
    int e = blockIdx.x * 256 + threadIdx.x;
    if (e < N_EDGES) {
        unsigned tsb = __float_as_uint(edge_ts[e]);   // ts>=0: bits order-preserving
        int d = dst[e];
        // hi-word filter: hi is monotone non-decreasing; 32b load can't tear.
        // tsb < hi => full key strictly loses => safe skip. Ties still atomic.
        unsigned cur_hi = ((const unsigned*)keys)[2 * d + 1];
        if (tsb >= cur_hi) {
            unsigned long long key =
                ((unsigned long long)tsb << 32) | (unsigned int)(e + 1);
            atomicMax(&keys[d], key);
        }
    }
}

// Frag-major W: wbF1[bIdx][kt][lane][8], bIdx=(g3*4+nq)*2+nf, kt 0..15 (W_ih, K-pad 512)
//              wbF2[bIdx][kt][lane][8], kt 0..3 (W_hh, K=128)
__global__ void convert_w_kernel(const float* __restrict__ Wih, const float* __restrict__ Whh,
                                 unsigned short* __restrict__ wbF1, unsigned short* __restrict__ wbF2) {
    int t = blockIdx.x * 256 + threadIdx.x;
    if (t < 24576) {
        int b = t >> 10, kt = (t >> 6) & 15, l = t & 63;
        int g3 = b >> 3, nq = (b >> 1) & 3, nf = b & 1;
        int srow = g3 * 128 + nq * 32 + nf * 16 + (l & 15);
        int scol = kt * 32 + (l >> 4) * 8;
        unsigned short v[8];
        #pragma unroll
        for (int j = 0; j < 8; ++j)
            v[j] = (scol + j < 484) ? f2bf(Wih[srow * 484 + scol + j]) : (unsigned short)0;
        uint4 pk;
        pk.x = (unsigned)v[0] | ((unsigned)v[1] << 16);
        pk.y = (unsigned)v[2] | ((unsigned)v[3] << 16);
        pk.z = (unsigned)v[4] | ((unsigned)v[5] << 16);
        pk.w = (unsigned)v[6] | ((unsigned)v[7] << 16);
        *(uint4*)&wbF1[(size_t)t * 8] = pk;
    } else if (t < 24576 + 6144) {
        int t2 = t - 24576;
        int b = t2 >> 8, kt = (t2 >> 6) & 3, l = t2 & 63;
        int g3 = b >> 3, nq = (b >> 1) & 3, nf = b & 1;
        int srow = g3 * 128 + nq * 32 + nf * 16 + (l & 15);
        int scol = kt * 32 + (l >> 4) * 8;
        unsigned short v[8];
        #pragma unroll
        for (int j = 0; j < 8; ++j) v[j] = f2bf(Whh[srow * 128 + scol + j]);
        uint4 pk;
        pk.x = (unsigned)v[0] | ((unsigned)v[1] << 16);
        pk.y = (unsigned)v[2] | ((unsigned)v[3] << 16);
        pk.z = (unsigned)v[4] | ((unsigned)v[5] << 16);
        pk.w = (unsigned)v[6] | ((unsigned)v[7] << 16);
        *(uint4*)&wbF2[(size_t)t2 * 8] = pk;
    }
}

// Fused: stage 128-node m_bar tile into 128KB LDS (bf16, XOR-swizzled), then
// 8-wave MFMA GEMM + GRU epilogue. B from frag-major global (L2-resident).
__global__ __launch_bounds__(NT, 2)
void gru_mfma_kernel(const int* __restrict__ src,
                     const float* __restrict__ edge_ts,
                     const float* __restrict__ ef,
                     const float* __restrict__ mem,
                     const float* __restrict__ lut,
                     const float* __restrict__ tw,
                     const float* __restrict__ tb,
                     const float* __restrict__ bih,
                     const float* __restrict__ bhh,
                     const unsigned short* __restrict__ wbF1,
                     const unsigned short* __restrict__ wbF2,
                     const unsigned long long* __restrict__ keys,
                     float* __restrict__ out) {
    __shared__ unsigned short Alds[BM * KPAD];   // 128 KB (gfx950 LDS = 160 KB/CU)
    const int tid = threadIdx.x;
    const int base = blockIdx.x * BM;

    // ---- staging: 4 threads per node ----
    {
        const int i = tid >> 2, l4 = tid & 3;
        const int n = base + i;
        if (n < N_NODES) {
            unsigned long long key = keys[n];
            const int has = (key != 0ULL);
            const int e = has ? (int)((unsigned)key - 1u) : 0;
            const int s = src[e];
            const float tv = edge_ts[e];
            const float d = tv - lut[s];
            if (l4 == 0)
                __builtin_nontemporal_store(has ? tv : lut[n],
                                            &out[(size_t)N_NODES * HDIM + n]);
            const int swi = i & 7;
            unsigned short* Arow = &Alds[i * KPAD];
            #pragma unroll
            for (int p = 0; p < 16; ++p) {
                const int gk = p * 4 + l4, k0 = gk * 8;   // 16B group 0..63
                float f[8];
                if (k0 < 384) {
                    const float* sp = (k0 < 128) ? mem + (size_t)s * HDIM + k0
                                    : (k0 < 256) ? mem + (size_t)n * HDIM + (k0 - 128)
                                                 : ef + (size_t)e * HDIM + (k0 - 256);
                    float4 v0 = *(const float4*)sp;
                    float4 v1 = *(const float4*)(sp + 4);
                    f[0]=v0.x; f[1]=v0.y; f[2]=v0.z; f[3]=v0.w;
                    f[4]=v1.x; f[5]=v1.y; f[6]=v1.z; f[7]=v1.w;
                } else {
                    #pragma unroll
                    for (int j2 = 0; j2 < 8; ++j2) {
                        int q = k0 - 384 + j2;
                        f[j2] = (q < TDIM) ? cosf(fmaf(d, tw[q], tb[q])) : 0.f;
                    }
                }
                uint4 pk;
                pk.x = (unsigned)f2bf(f[0]) | ((unsigned)f2bf(f[1]) << 16);
                pk.y = (unsigned)f2bf(f[2]) | ((unsigned)f2bf(f[3]) << 16);
                pk.z = (unsigned)f2bf(f[4]) | ((unsigned)f2bf(f[5]) << 16);
                pk.w = (unsigned)f2bf(f[6]) | ((unsigned)f2bf(f[7]) << 16);
                *(uint4*)&Arow[(size_t)(gk ^ swi) * 8] = pk;
            }
        }
    }
    __syncthreads();

    // ---- MFMA GEMMs: 8 waves = 2 M-halves x 4 N-quarters ----
    const int w = tid >> 6, l = tid & 63;
    const int mh = w >> 2, nq = w & 3;
    const int lr = l & 15, lh = l >> 4;

    const f32x4 fzero = {0.f, 0.f, 0.f, 0.f};
    f32x4 acc[4][2][4];  // q=0 r(i+h), q=1 z(i+h), q=2 i_n, q=3 h_n
    #pragma unroll
    for (int q = 0; q < 4; ++q)
        #pragma unroll
        for (int nf = 0; nf < 2; ++nf)
            #pragma unroll
            for (int mf = 0; mf < 4; ++mf) acc[q][nf][mf] = fzero;

    // GEMM1: gi = A(K=512) @ W_ih^T
    #pragma unroll 4
    for (int kt = 0; kt < KPAD / 32; ++kt) {
        const int k0 = kt * 32;
        short8v a[4];
        #pragma unroll
        for (int mf = 0; mf < 4; ++mf) {
            const int row = mh * 64 + mf * 16 + lr;
            a[mf] = *(const short8v*)&Alds[row * KPAD + ((k0 + lh * 8) ^ ((row & 7) << 3))];
        }
        #pragma unroll
        for (int g3 = 0; g3 < 3; ++g3)
            #pragma unroll
            for (int nf = 0; nf < 2; ++nf) {
                const int bidx = (g3 * 4 + nq) * 2 + nf;
                short8v b = *(const short8v*)&wbF1[((size_t)(bidx * 16 + kt) * 64 + l) * 8];
                #pragma unroll
                for (int mf = 0; mf < 4; ++mf)
                    acc[g3][nf][mf] = __builtin_amdgcn_mfma_f32_16x16x32_bf16(
                        a[mf], b, acc[g3][nf][mf], 0, 0, 0);
            }
    }
    // GEMM2: gh = mem_s @ W_hh^T  (A k-slice 128..256)
    #pragma unroll
    for (int kt = 0; kt < 4; ++kt) {
        const int kA = 128 + kt * 32;
        short8v a[4];
        #pragma unroll
        for (int mf = 0; mf < 4; ++mf) {
            const int row = mh * 64 + mf * 16 + lr;
            a[mf] = *(const short8v*)&Alds[row * KPAD + ((kA + lh * 8) ^ ((row & 7) << 3))];
        }
        #pragma unroll
        for (int g3 = 0; g3 < 3; ++g3)
            #pragma unroll
            for (int nf = 0; nf < 2; ++nf) {
                const int bidx = (g3 * 4 + nq) * 2 + nf;
                short8v b = *(const short8v*)&wbF2[((size_t)(bidx * 4 + kt) * 64 + l) * 8];
                const int q = (g3 < 2) ? g3 : 3;
                #pragma unroll
                for (int mf = 0; mf < 4; ++mf)
                    acc[q][nf][mf] = __builtin_amdgcn_mfma_f32_16x16x32_bf16(
                        a[mf], b, acc[q][nf][mf], 0, 0, 0);
            }
    }

    // ---- GRU epilogue (nt loads/stores: don't evict weights from L2) ----
    float br[2], bz[2], bin[2], bhn[2];
    #pragma unroll
    for (int nf = 0; nf < 2; ++nf) {
        const int c = nq * 32 + nf * 16 + lr;
        br[nf] = bih[c] + bhh[c];
        bz[nf] = bih[HDIM + c] + bhh[HDIM + c];
        bin[nf] = bih[2 * HDIM + c];
        bhn[nf] = bhh[2 * HDIM + c];
    }
    #pragma unroll
    for (int mf = 0; mf < 4; ++mf)
        #pragma unroll
        for (int ii = 0; ii < 4; ++ii) {
            const int row = mh * 64 + mf * 16 + lh * 4 + ii;
            const int node = base + row;
            if (node >= N_NODES) continue;
            const bool has = keys[node] != 0ULL;
            #pragma unroll
            for (int nf = 0; nf < 2; ++nf) {
                const int c = nq * 32 + nf * 16 + lr;
                const float r = sigmoidf_(acc[0][nf][mf][ii] + br[nf]);
                const float z = sigmoidf_(acc[1][nf][mf][ii] + bz[nf]);
                const float ng = tanhf_(acc[2][nf][mf][ii] + bin[nf] +
                                        r * (acc[3][nf][mf][ii] + bhn[nf]));
                const float h = __builtin_nontemporal_load(&mem[(size_t)node * HDIM + c]);
                __builtin_nontemporal_store(has ? (1.f - z) * ng + z * h : h,
                                            &out[(size_t)node * HDIM + c]);
            }
        }
}

extern "C" void kernel_launch(void* const* d_in, const int* in_sizes, int n_in,
                              void* d_out, int out_size, void* d_ws, size_t ws_size,
                              hipStream_t stream) {
    const int* src       = (const int*)d_in[0];
    const int* dst       = (const int*)d_in[1];
    const float* edge_ts = (const float*)d_in[2];
    const float* ef      = (const float*)d_in[3];
    const float* mem     = (const float*)d_in[4];
    const float* lut     = (const float*)d_in[5];
    const float* tw      = (const float*)d_in[6];
    const float* tb      = (const float*)d_in[7];
    const float* Wih     = (const float*)d_in[8];
    const float* Whh     = (const float*)d_in[9];
    const float* bih     = (const float*)d_in[10];
    const float* bhh     = (const float*)d_in[11];
    float* out = (float*)d_out;

    char* ws = (char*)d_ws;
    unsigned long long* keys = (unsigned long long*)ws;      // 400000 B (region 512K)
    unsigned short* wbF1 = (unsigned short*)(ws + 524288);   // 393216 B
    unsigned short* wbF2 = (unsigned short*)(ws + 917504);   //  98304 B

    hipMemsetAsync(keys, 0, (size_t)N_NODES * 8, stream);
    scan_edges_kernel<<<(N_EDGES + 255) / 256, 256, 0, stream>>>(dst, edge_ts, keys);
    convert_w_kernel<<<(24576 + 6144 + 255) / 256, 256, 0, stream>>>(Wih, Whh, wbF1, wbF2);
    gru_mfma_kernel<<<NBLOCKS, NT, 0, stream>>>(
        src, edge_ts, ef, mem, lut, tw, tb, bih, bhh, wbF1, wbF2, keys, out);
}